// Round 8
// baseline (269.303 us; speedup 1.0000x reference)
//
#include <hip/hip_runtime.h>

#define N_NODES 50000
#define NIN 128
#define NOUT 64
#define EIN 32
#define N_EDGES 400000
#define N_UNITS (2 * N_EDGES)
#define ALPHA 0.2f
#define CAP 64  // per-node bucket capacity; P(deg>64) ~ 1e-18 for this graph
#define N_GATHER_BLOCKS 12500

__device__ __forceinline__ int clampi(int x) {
  return min(max(x, 0), N_NODES - 1);
}

// round f32 -> bf16 (RNE), result in LOW 16 bits
__device__ __forceinline__ unsigned bf16_lo(float f) {
  unsigned u = __float_as_uint(f);
  return (u + 0x7FFFu + ((u >> 16) & 1u)) >> 16;
}
// round f32 -> bf16 (RNE), result left in HIGH 16 bits
__device__ __forceinline__ unsigned bf16_hi(float f) {
  unsigned u = __float_as_uint(f);
  return (u + 0x7FFFu + ((u >> 16) & 1u)) & 0xFFFF0000u;
}

// ---------------------------------------------------------------------------
// Kernel 1: h = node_fts @ W + b -> out[v][0:64] (f32) + bf16 copy hb +
// A = h.a1, B = h.a2, hn = ||h||.
// W COLUMN IS REGISTER-RESIDENT: lane j holds W[:,j] in 128 VGPRs (fill is
// fully coalesced, 32 KB/block from L2).  Inner loop reads the nf row with
// wave-uniform float4 loads (1 line/request, L1-served) + register FMAs.
// No LDS, no barriers.  Previous version issued 128 ds_read_b32 per node
// (~750 cyc, the 61 us wall); FMA-issue floor is ~5 us.
// ---------------------------------------------------------------------------
__global__ __launch_bounds__(256, 2) void k_gemm(
    const float* __restrict__ nf, const float* __restrict__ W,
    const float* __restrict__ b, const float* __restrict__ a,
    float* __restrict__ out, unsigned short* __restrict__ hb,
    float* __restrict__ A, float* __restrict__ B, float* __restrict__ hn) {
  int t = threadIdx.x;
  int j = t & 63, w = t >> 6;
  float wk[NIN];
#pragma unroll
  for (int k = 0; k < NIN; ++k) wk[k] = W[(size_t)k * NOUT + j];
  float bj = b[j], a1j = a[j], a2j = a[64 + j];
  for (int v = blockIdx.x * 4 + w; v < N_NODES; v += gridDim.x * 4) {
    const float4* rp = (const float4*)(nf + (size_t)v * NIN);
    float ac0 = bj, ac1 = 0.f, ac2 = 0.f, ac3 = 0.f;
#pragma unroll
    for (int q = 0; q < 8; ++q) {
      float4 r0 = rp[4 * q + 0];
      float4 r1 = rp[4 * q + 1];
      float4 r2 = rp[4 * q + 2];
      float4 r3 = rp[4 * q + 3];
      int k = 16 * q;
      ac0 = fmaf(r0.x, wk[k + 0], ac0);
      ac0 = fmaf(r0.y, wk[k + 1], ac0);
      ac0 = fmaf(r0.z, wk[k + 2], ac0);
      ac0 = fmaf(r0.w, wk[k + 3], ac0);
      ac1 = fmaf(r1.x, wk[k + 4], ac1);
      ac1 = fmaf(r1.y, wk[k + 5], ac1);
      ac1 = fmaf(r1.z, wk[k + 6], ac1);
      ac1 = fmaf(r1.w, wk[k + 7], ac1);
      ac2 = fmaf(r2.x, wk[k + 8], ac2);
      ac2 = fmaf(r2.y, wk[k + 9], ac2);
      ac2 = fmaf(r2.z, wk[k + 10], ac2);
      ac2 = fmaf(r2.w, wk[k + 11], ac2);
      ac3 = fmaf(r3.x, wk[k + 12], ac3);
      ac3 = fmaf(r3.y, wk[k + 13], ac3);
      ac3 = fmaf(r3.z, wk[k + 14], ac3);
      ac3 = fmaf(r3.w, wk[k + 15], ac3);
    }
    float acc = (ac0 + ac1) + (ac2 + ac3);
    out[(size_t)v * 128 + j] = acc;  // exact f32 h into output row
    hb[(size_t)v * NOUT + j] = (unsigned short)bf16_lo(acc);
    float pa = acc * a1j, pb = acc * a2j, pn = acc * acc;
    for (int o = 32; o > 0; o >>= 1) {
      pa += __shfl_down(pa, o, 64);
      pb += __shfl_down(pb, o, 64);
      pn += __shfl_down(pn, o, 64);
    }
    if (j == 0) { A[v] = pa; B[v] = pb; hn[v] = sqrtf(pn); }
  }
}

// ---------------------------------------------------------------------------
// Kernel 2: per edge compute leaky-relu logits both directions and place
// PACKED 4-byte entries (bf16(l) high | dst low) directly into fixed-CAP
// buckets: csr[s*CAP + atomicAdd(&cnt[s],1)].
// ---------------------------------------------------------------------------
__global__ __launch_bounds__(256) void k_edge1(
    const int* __restrict__ eb, const float* __restrict__ ef,
    const float* __restrict__ a, const float* __restrict__ A,
    const float* __restrict__ B, int* __restrict__ cnt,
    unsigned* __restrict__ csr) {
  __shared__ float a3s[EIN];
  if (threadIdx.x < EIN) a3s[threadIdx.x] = a[128 + threadIdx.x];
  __syncthreads();
  int i = blockIdx.x * blockDim.x + threadIdx.x;
  if (i >= N_EDGES) return;
  int2 sd = ((const int2*)eb)[i];
  int s = clampi(sd.x), d = clampi(sd.y);
  const float4* efp = (const float4*)(ef + (size_t)i * EIN);
  float c = 0.f;
#pragma unroll
  for (int q = 0; q < 8; ++q) {
    float4 u = efp[q];
    c += u.x * a3s[4 * q + 0] + u.y * a3s[4 * q + 1] +
         u.z * a3s[4 * q + 2] + u.w * a3s[4 * q + 3];
  }
  float zf = A[s] + B[d] + c;  // forward: src=s, dst=d
  float zr = A[d] + B[s] + c;  // reverse: src=d, dst=s
  float lf = zf > 0.f ? zf : ALPHA * zf;
  float lr = zr > 0.f ? zr : ALPHA * zr;
  int ps = atomicAdd(&cnt[s], 1);
  if (ps < CAP) csr[(size_t)s * CAP + ps] = bf16_hi(lf) | (unsigned)d;
  int pd = atomicAdd(&cnt[d], 1);
  if (pd < CAP) csr[(size_t)d * CAP + pd] = bf16_hi(lr) | (unsigned)s;
}

// ---------------------------------------------------------------------------
// Kernel 3: one wave per node; 8 bucket entries per wave-load.
//   lane l: group g = l>>3 (entry within batch), octet p = l&7 (cols 8p..8p+7).
//   Each lane gathers uint4 = 16 B = 8 bf16 cols of its group's row.
//   Segment base is the computed v*CAP; length cnt[v].
// Grid is exactly 12500*4 waves = 50000 nodes, so no early-return.
// ---------------------------------------------------------------------------
__global__ __launch_bounds__(256) void k_gather(
    const uint4* __restrict__ hb4, const float* __restrict__ hn,
    const int* __restrict__ cnt, const unsigned* __restrict__ csr,
    const float* __restrict__ scale_p, float* __restrict__ out,
    double* __restrict__ parts) {
  __shared__ double s1s[4], s2s[4];
  float scale = scale_p[0];
  int t = threadIdx.x;
  int w = t >> 6;
  int l = t & 63;
  int g = l >> 3;  // entry group 0..7
  int p = l & 7;   // col octet
  int v = blockIdx.x * 4 + w;  // grid exactly covers N_NODES
  int deg = min(__builtin_amdgcn_readfirstlane(cnt[v]), CAP);
  int k0 = v * CAP;
  int k1 = k0 + deg;
  float mA[8] = {0.f, 0.f, 0.f, 0.f, 0.f, 0.f, 0.f, 0.f};
  float mB[8] = {0.f, 0.f, 0.f, 0.f, 0.f, 0.f, 0.f, 0.f};
  float Se = 0.f, L1 = 0.f, L2 = 0.f;
  unsigned E = csr[k0 + g];  // always within the CAP-64 bucket
  for (int kb = k0; kb < k1; kb += 8) {
    unsigned C = E;
    if (kb + 8 < k1) E = csr[kb + 8 + g];
    bool valid = (kb + g) < k1;
    int idx = valid ? (int)(C & 0xFFFFu) : v;  // safe row when masked
    float lk = valid ? __uint_as_float(C & 0xFFFF0000u) : 0.f;
    float vm = valid ? 1.f : 0.f;
    uint4 q = hb4[(size_t)idx * 8 + p];  // 8 bf16 cols of row idx
    float hv[8];
    hv[0] = __uint_as_float(q.x << 16);
    hv[1] = __uint_as_float(q.x & 0xFFFF0000u);
    hv[2] = __uint_as_float(q.y << 16);
    hv[3] = __uint_as_float(q.y & 0xFFFF0000u);
    hv[4] = __uint_as_float(q.z << 16);
    hv[5] = __uint_as_float(q.z & 0xFFFF0000u);
    hv[6] = __uint_as_float(q.w << 16);
    hv[7] = __uint_as_float(q.w & 0xFFFF0000u);
    Se += valid ? __expf(lk) : 0.f;
    L1 += lk;
    L2 += lk * lk;
#pragma unroll
    for (int c = 0; c < 8; ++c) {
      mA[c] = fmaf(hv[c], lk, mA[c]);   // lk==0 when masked
      mB[c] = fmaf(hv[c], vm, mB[c]);   // vm==0 when masked
    }
  }
  // merge scalar partials across the 8 groups (bits 3..5 of lane id)
  for (int o = 8; o < 64; o <<= 1) {
    Se += __shfl_xor(Se, o, 64);
    L1 += __shfl_xor(L1, o, 64);
    L2 += __shfl_xor(L2, o, 64);
  }
  float logS = (deg > 0) ? logf(Se) : 0.f;
  float mf[8];
#pragma unroll
  for (int c = 0; c < 8; ++c) mf[c] = mA[c] - logS * mB[c];
  // merge message columns across groups
  for (int o = 8; o < 64; o <<= 1) {
#pragma unroll
    for (int c = 0; c < 8; ++c) mf[c] += __shfl_xor(mf[c], o, 64);
  }
  float nr = 0.f;
#pragma unroll
  for (int c = 0; c < 8; ++c) nr += mf[c] * mf[c];
  for (int o = 1; o < 8; o <<= 1) nr += __shfl_xor(nr, o, 64);
  nr = sqrtf(nr);
  float fac = hn[v] * scale / fmaxf(nr, 1e-12f);
  if (g == 0) {
    float4 s0 = make_float4(mf[0] * fac, mf[1] * fac, mf[2] * fac, mf[3] * fac);
    float4 s1 = make_float4(mf[4] * fac, mf[5] * fac, mf[6] * fac, mf[7] * fac);
    float* op = out + (size_t)v * 128 + 64 + p * 8;
    ((float4*)op)[0] = s0;
    ((float4*)op)[1] = s1;
  }
  // variance partials per wave (closed form; identical in all lanes)
  if (l == 0) {
    double dls = (double)logS, dl1 = (double)L1, dl2 = (double)L2;
    double dd = (double)deg;
    s1s[w] = dl1 - dd * dls;
    s2s[w] = dl2 - 2.0 * dls * dl1 + dd * dls * dls;
  }
  __syncthreads();
  if (t == 0) {
    // plain per-block store — no contention
    parts[2 * blockIdx.x] = s1s[0] + s1s[1] + s1s[2] + s1s[3];
    parts[2 * blockIdx.x + 1] = s2s[0] + s2s[1] + s2s[2] + s2s[3];
  }
}

// ---------------------------------------------------------------------------
// Kernel 4: reduce 12500 per-block partials -> att_var -> out tail (f32)
// ---------------------------------------------------------------------------
__global__ __launch_bounds__(256) void k_var(const double* __restrict__ parts,
                                             float* __restrict__ out) {
  __shared__ double s1[256], s2[256];
  int t = threadIdx.x;
  double a1 = 0.0, a2 = 0.0;
  for (int i = t; i < N_GATHER_BLOCKS; i += 256) {
    a1 += parts[2 * i];
    a2 += parts[2 * i + 1];
  }
  s1[t] = a1;
  s2[t] = a2;
  __syncthreads();
  for (int o = 128; o > 0; o >>= 1) {
    if (t < o) {
      s1[t] += s1[t + o];
      s2[t] += s2[t + o];
    }
    __syncthreads();
  }
  if (t == 0) {
    double M = (double)N_UNITS;
    double var = (s2[0] - s1[0] * s1[0] / M) / (M - 1.0);
    out[(size_t)N_NODES * 128] = (float)var;
  }
}

extern "C" void kernel_launch(void* const* d_in, const int* in_sizes, int n_in,
                              void* d_out, int out_size, void* d_ws,
                              size_t ws_size, hipStream_t stream) {
  const float* nf = (const float*)d_in[0];
  const float* ef = (const float*)d_in[1];
  const int* eb = (const int*)d_in[2];
  const float* W = (const float*)d_in[3];
  const float* b = (const float*)d_in[4];
  const float* a = (const float*)d_in[5];
  const float* scale_p = (const float*)d_in[6];
  float* out = (float*)d_out;  // 6,400,001 f32

  char* ws = (char*)d_ws;
  unsigned short* hb = (unsigned short*)(ws + 0);  //  6,400,000 B (bf16 h)
  unsigned* csr = (unsigned*)(ws + 6400000);       // 12,800,000 B (50000x64)
  float* A = (float*)(ws + 19200000);              //    200,000 B
  float* B = (float*)(ws + 19400000);              //    200,000 B
  float* hn = (float*)(ws + 19600000);             //    200,000 B
  int* cnt = (int*)(ws + 19800000);                //    200,000 B
  double* parts = (double*)(ws + 20000000);        //    200,000 B (12500 x 2)

  // zero cnt only (csr tail is read masked; parts fully overwritten)
  hipMemsetAsync(ws + 19800000, 0, 200000, stream);

  k_gemm<<<1024, 256, 0, stream>>>(nf, W, b, a, out, hb, A, B, hn);
  k_edge1<<<(N_EDGES + 255) / 256, 256, 0, stream>>>(eb, ef, a, A, B, cnt,
                                                     csr);
  k_gather<<<N_GATHER_BLOCKS, 256, 0, stream>>>((const uint4*)hb, hn, cnt, csr,
                                                scale_p, out, parts);
  k_var<<<1, 256, 0, stream>>>(parts, out);
}

// Round 9
// 234.845 us; speedup vs baseline: 1.1467x; 1.1467x over previous
//
#include <hip/hip_runtime.h>

#define N_NODES 50000
#define NIN 128
#define NOUT 64
#define EIN 32
#define N_EDGES 400000
#define N_UNITS (2 * N_EDGES)
#define ALPHA 0.2f
#define CAP 64  // per-node bucket capacity; P(deg>64) ~ 1e-18 for this graph
#define N_GATHER_BLOCKS 12500

__device__ __forceinline__ int clampi(int x) {
  return min(max(x, 0), N_NODES - 1);
}

// round f32 -> bf16 (RNE), result in LOW 16 bits
__device__ __forceinline__ unsigned bf16_lo(float f) {
  unsigned u = __float_as_uint(f);
  return (u + 0x7FFFu + ((u >> 16) & 1u)) >> 16;
}
// round f32 -> bf16 (RNE), result left in HIGH 16 bits
__device__ __forceinline__ unsigned bf16_hi(float f) {
  unsigned u = __float_as_uint(f);
  return (u + 0x7FFFu + ((u >> 16) & 1u)) & 0xFFFF0000u;
}

// ---------------------------------------------------------------------------
// Kernel 1: h = node_fts @ W + b -> out[v][0:64] (f32) + bf16 copy hb +
// A = h.a1, B = h.a2, hn = ||h||.
// K-SPLIT REGISTER W: lane j of wave w holds W[32w..32w+32][j] in 32 VGPRs
// (small enough that the compiler provably keeps it register-resident —
// R8's wk[128] was demoted, VGPR_Count=128 proved it).  Per iteration the
// block stages 8 nf rows via coalesced per-lane float4 loads (4 KB
// contiguous), each wave computes 8 partial dots over its k-quarter
// (wave-uniform LDS broadcasts + register FMAs), partials reduce through
// an 8 KB LDS buffer, each wave epilogues 2 nodes.
// W LDS traffic: 0 (was 32 KB/node = 1.6 GB total, the 61 us wall).
// ---------------------------------------------------------------------------
__global__ __launch_bounds__(256) void k_gemm(
    const float* __restrict__ nf, const float* __restrict__ W,
    const float* __restrict__ b, const float* __restrict__ a,
    float* __restrict__ out, unsigned short* __restrict__ hb,
    float* __restrict__ A, float* __restrict__ B, float* __restrict__ hn) {
  __shared__ float rows[8][NIN];      // 4 KB
  __shared__ float part[4][8][NOUT];  // 8 KB
  int t = threadIdx.x;
  int w = t >> 6, j = t & 63;
  float wq[32];
#pragma unroll
  for (int i = 0; i < 32; ++i) wq[i] = W[(size_t)(32 * w + i) * NOUT + j];
  float bj = b[j], a1j = a[j], a2j = a[64 + j];
  for (int base = blockIdx.x * 8; base < N_NODES; base += gridDim.x * 8) {
    // stage 8 rows coalesced: thread t -> row t>>5, float4 slot t&31
    {
      const float4* src =
          (const float4*)(nf + (size_t)(base + (t >> 5)) * NIN);
      ((float4*)rows[t >> 5])[t & 31] = src[t & 31];
    }
    __syncthreads();
    // wave w: partial dots over k in [32w, 32w+32) for all 8 rows
    float ac[8] = {0.f, 0.f, 0.f, 0.f, 0.f, 0.f, 0.f, 0.f};
#pragma unroll
    for (int q = 0; q < 8; ++q) {
      float4 x[8];
#pragma unroll
      for (int r = 0; r < 8; ++r)
        x[r] = ((const float4*)&rows[r][32 * w])[q];
#pragma unroll
      for (int r = 0; r < 8; ++r) {
        ac[r] = fmaf(x[r].x, wq[4 * q + 0], ac[r]);
        ac[r] = fmaf(x[r].y, wq[4 * q + 1], ac[r]);
        ac[r] = fmaf(x[r].z, wq[4 * q + 2], ac[r]);
        ac[r] = fmaf(x[r].w, wq[4 * q + 3], ac[r]);
      }
    }
#pragma unroll
    for (int r = 0; r < 8; ++r) part[w][r][j] = ac[r];
    __syncthreads();
    // wave w reduces + epilogues nodes r = w and r = w+4
#pragma unroll
    for (int s = 0; s < 2; ++s) {
      int r = w + 4 * s;
      int v = base + r;
      float acc = bj + ((part[0][r][j] + part[1][r][j]) +
                        (part[2][r][j] + part[3][r][j]));
      out[(size_t)v * 128 + j] = acc;  // exact f32 h into output row
      hb[(size_t)v * NOUT + j] = (unsigned short)bf16_lo(acc);
      float pa = acc * a1j, pb = acc * a2j, pn = acc * acc;
      for (int o = 32; o > 0; o >>= 1) {
        pa += __shfl_down(pa, o, 64);
        pb += __shfl_down(pb, o, 64);
        pn += __shfl_down(pn, o, 64);
      }
      if (j == 0) { A[v] = pa; B[v] = pb; hn[v] = sqrtf(pn); }
    }
    __syncthreads();
  }
}

// ---------------------------------------------------------------------------
// Kernel 2: per edge compute leaky-relu logits both directions and place
// PACKED 4-byte entries (bf16(l) high | dst low) directly into fixed-CAP
// buckets: csr[s*CAP + atomicAdd(&cnt[s],1)].
// ---------------------------------------------------------------------------
__global__ __launch_bounds__(256) void k_edge1(
    const int* __restrict__ eb, const float* __restrict__ ef,
    const float* __restrict__ a, const float* __restrict__ A,
    const float* __restrict__ B, int* __restrict__ cnt,
    unsigned* __restrict__ csr) {
  __shared__ float a3s[EIN];
  if (threadIdx.x < EIN) a3s[threadIdx.x] = a[128 + threadIdx.x];
  __syncthreads();
  int i = blockIdx.x * blockDim.x + threadIdx.x;
  if (i >= N_EDGES) return;
  int2 sd = ((const int2*)eb)[i];
  int s = clampi(sd.x), d = clampi(sd.y);
  const float4* efp = (const float4*)(ef + (size_t)i * EIN);
  float c = 0.f;
#pragma unroll
  for (int q = 0; q < 8; ++q) {
    float4 u = efp[q];
    c += u.x * a3s[4 * q + 0] + u.y * a3s[4 * q + 1] +
         u.z * a3s[4 * q + 2] + u.w * a3s[4 * q + 3];
  }
  float zf = A[s] + B[d] + c;  // forward: src=s, dst=d
  float zr = A[d] + B[s] + c;  // reverse: src=d, dst=s
  float lf = zf > 0.f ? zf : ALPHA * zf;
  float lr = zr > 0.f ? zr : ALPHA * zr;
  int ps = atomicAdd(&cnt[s], 1);
  if (ps < CAP) csr[(size_t)s * CAP + ps] = bf16_hi(lf) | (unsigned)d;
  int pd = atomicAdd(&cnt[d], 1);
  if (pd < CAP) csr[(size_t)d * CAP + pd] = bf16_hi(lr) | (unsigned)s;
}

// ---------------------------------------------------------------------------
// Kernel 3: one wave per node; 8 bucket entries per wave-load.
//   lane l: group g = l>>3 (entry within batch), octet p = l&7 (cols 8p..8p+7).
//   Each lane gathers uint4 = 16 B = 8 bf16 cols of its group's row.
//   Segment base is the computed v*CAP; length cnt[v].
// Grid is exactly 12500*4 waves = 50000 nodes, so no early-return.
// ---------------------------------------------------------------------------
__global__ __launch_bounds__(256) void k_gather(
    const uint4* __restrict__ hb4, const float* __restrict__ hn,
    const int* __restrict__ cnt, const unsigned* __restrict__ csr,
    const float* __restrict__ scale_p, float* __restrict__ out,
    double* __restrict__ parts) {
  __shared__ double s1s[4], s2s[4];
  float scale = scale_p[0];
  int t = threadIdx.x;
  int w = t >> 6;
  int l = t & 63;
  int g = l >> 3;  // entry group 0..7
  int p = l & 7;   // col octet
  int v = blockIdx.x * 4 + w;  // grid exactly covers N_NODES
  int deg = min(__builtin_amdgcn_readfirstlane(cnt[v]), CAP);
  int k0 = v * CAP;
  int k1 = k0 + deg;
  float mA[8] = {0.f, 0.f, 0.f, 0.f, 0.f, 0.f, 0.f, 0.f};
  float mB[8] = {0.f, 0.f, 0.f, 0.f, 0.f, 0.f, 0.f, 0.f};
  float Se = 0.f, L1 = 0.f, L2 = 0.f;
  unsigned E = csr[k0 + g];  // always within the CAP-64 bucket
  for (int kb = k0; kb < k1; kb += 8) {
    unsigned C = E;
    if (kb + 8 < k1) E = csr[kb + 8 + g];
    bool valid = (kb + g) < k1;
    int idx = valid ? (int)(C & 0xFFFFu) : v;  // safe row when masked
    float lk = valid ? __uint_as_float(C & 0xFFFF0000u) : 0.f;
    float vm = valid ? 1.f : 0.f;
    uint4 q = hb4[(size_t)idx * 8 + p];  // 8 bf16 cols of row idx
    float hv[8];
    hv[0] = __uint_as_float(q.x << 16);
    hv[1] = __uint_as_float(q.x & 0xFFFF0000u);
    hv[2] = __uint_as_float(q.y << 16);
    hv[3] = __uint_as_float(q.y & 0xFFFF0000u);
    hv[4] = __uint_as_float(q.z << 16);
    hv[5] = __uint_as_float(q.z & 0xFFFF0000u);
    hv[6] = __uint_as_float(q.w << 16);
    hv[7] = __uint_as_float(q.w & 0xFFFF0000u);
    Se += valid ? __expf(lk) : 0.f;
    L1 += lk;
    L2 += lk * lk;
#pragma unroll
    for (int c = 0; c < 8; ++c) {
      mA[c] = fmaf(hv[c], lk, mA[c]);   // lk==0 when masked
      mB[c] = fmaf(hv[c], vm, mB[c]);   // vm==0 when masked
    }
  }
  // merge scalar partials across the 8 groups (bits 3..5 of lane id)
  for (int o = 8; o < 64; o <<= 1) {
    Se += __shfl_xor(Se, o, 64);
    L1 += __shfl_xor(L1, o, 64);
    L2 += __shfl_xor(L2, o, 64);
  }
  float logS = (deg > 0) ? logf(Se) : 0.f;
  float mf[8];
#pragma unroll
  for (int c = 0; c < 8; ++c) mf[c] = mA[c] - logS * mB[c];
  // merge message columns across groups
  for (int o = 8; o < 64; o <<= 1) {
#pragma unroll
    for (int c = 0; c < 8; ++c) mf[c] += __shfl_xor(mf[c], o, 64);
  }
  float nr = 0.f;
#pragma unroll
  for (int c = 0; c < 8; ++c) nr += mf[c] * mf[c];
  for (int o = 1; o < 8; o <<= 1) nr += __shfl_xor(nr, o, 64);
  nr = sqrtf(nr);
  float fac = hn[v] * scale / fmaxf(nr, 1e-12f);
  if (g == 0) {
    float4 s0 = make_float4(mf[0] * fac, mf[1] * fac, mf[2] * fac, mf[3] * fac);
    float4 s1 = make_float4(mf[4] * fac, mf[5] * fac, mf[6] * fac, mf[7] * fac);
    float* op = out + (size_t)v * 128 + 64 + p * 8;
    ((float4*)op)[0] = s0;
    ((float4*)op)[1] = s1;
  }
  // variance partials per wave (closed form; identical in all lanes)
  if (l == 0) {
    double dls = (double)logS, dl1 = (double)L1, dl2 = (double)L2;
    double dd = (double)deg;
    s1s[w] = dl1 - dd * dls;
    s2s[w] = dl2 - 2.0 * dls * dl1 + dd * dls * dls;
  }
  __syncthreads();
  if (t == 0) {
    // plain per-block store — no contention
    parts[2 * blockIdx.x] = s1s[0] + s1s[1] + s1s[2] + s1s[3];
    parts[2 * blockIdx.x + 1] = s2s[0] + s2s[1] + s2s[2] + s2s[3];
  }
}

// ---------------------------------------------------------------------------
// Kernel 4: reduce 12500 per-block partials -> att_var -> out tail (f32)
// ---------------------------------------------------------------------------
__global__ __launch_bounds__(256) void k_var(const double* __restrict__ parts,
                                             float* __restrict__ out) {
  __shared__ double s1[256], s2[256];
  int t = threadIdx.x;
  double a1 = 0.0, a2 = 0.0;
  for (int i = t; i < N_GATHER_BLOCKS; i += 256) {
    a1 += parts[2 * i];
    a2 += parts[2 * i + 1];
  }
  s1[t] = a1;
  s2[t] = a2;
  __syncthreads();
  for (int o = 128; o > 0; o >>= 1) {
    if (t < o) {
      s1[t] += s1[t + o];
      s2[t] += s2[t + o];
    }
    __syncthreads();
  }
  if (t == 0) {
    double M = (double)N_UNITS;
    double var = (s2[0] - s1[0] * s1[0] / M) / (M - 1.0);
    out[(size_t)N_NODES * 128] = (float)var;
  }
}

extern "C" void kernel_launch(void* const* d_in, const int* in_sizes, int n_in,
                              void* d_out, int out_size, void* d_ws,
                              size_t ws_size, hipStream_t stream) {
  const float* nf = (const float*)d_in[0];
  const float* ef = (const float*)d_in[1];
  const int* eb = (const int*)d_in[2];
  const float* W = (const float*)d_in[3];
  const float* b = (const float*)d_in[4];
  const float* a = (const float*)d_in[5];
  const float* scale_p = (const float*)d_in[6];
  float* out = (float*)d_out;  // 6,400,001 f32

  char* ws = (char*)d_ws;
  unsigned short* hb = (unsigned short*)(ws + 0);  //  6,400,000 B (bf16 h)
  unsigned* csr = (unsigned*)(ws + 6400000);       // 12,800,000 B (50000x64)
  float* A = (float*)(ws + 19200000);              //    200,000 B
  float* B = (float*)(ws + 19400000);              //    200,000 B
  float* hn = (float*)(ws + 19600000);             //    200,000 B
  int* cnt = (int*)(ws + 19800000);                //    200,000 B
  double* parts = (double*)(ws + 20000000);        //    200,000 B (12500 x 2)

  // zero cnt only (csr tail is read masked; parts fully overwritten)
  hipMemsetAsync(ws + 19800000, 0, 200000, stream);

  k_gemm<<<1024, 256, 0, stream>>>(nf, W, b, a, out, hb, A, B, hn);
  k_edge1<<<(N_EDGES + 255) / 256, 256, 0, stream>>>(eb, ef, a, A, B, cnt,
                                                     csr);
  k_gather<<<N_GATHER_BLOCKS, 256, 0, stream>>>((const uint4*)hb, hn, cnt, csr,
                                                scale_p, out, parts);
  k_var<<<1, 256, 0, stream>>>(parts, out);
}